// Round 13
// baseline (78.777 us; speedup 1.0000x reference)
//
#include <hip/hip_runtime.h>

// Encoder: per-atom top-T nearest grid points -> sum_t rbf[33] (x) (sh[9]*n*w)
// R12 lesson: budget reconstruction says enc_accum (~30us) is the whale, at
// ~4x roofline -- stalled on the per-point serial chain (16-step sincos
// recurrence = 32 dependent FMAs). Break the chain with independent v_sin/v_cos.
// 4 dispatches:
// K1 hist_store: full scan; 256-bin clamped coarse hist; (bits,idx) append
// K2 fine      : redundant coarse scan -> b1; fine hist -> ghist2[a][512]
// K3 accum     : stage 2KB fine hist, scan -> thr; filter pairs, bf16 MFMA,
//                LDS cross-wave reduce, one plain 297-float store per block
// K4 reduce    : sum 128 chunk-partials per atom -> out

typedef float f32x4 __attribute__((ext_vector_type(4)));
typedef int   i32x4 __attribute__((ext_vector_type(4)));

#define SLICES 32
#define NB1    256           // coarse bins (clamped)
#define NB2    512           // fine bins: bits[17:9] within crossing bin
#define CLAMP0 4000u         // bits>>18 below this (d2<~0.25) -> bin 0
#define CHA    4             // accum chunks per segment
#define NCHUNK (SLICES * CHA)
#define PBSTR  304           // partials row stride
#define CUT25  0x41C80000u   // __float_as_uint(25.0f) == CUTOFF^2 bits

__device__ __forceinline__ unsigned d2bits(float px, float py, float pz,
                                           float gx, float gy, float gz) {
  float dx = px - gx, dy = py - gy, dz = pz - gz;
  float d2 = __fmaf_rn(dx, dx, __fmaf_rn(dy, dy, __fmul_rn(dz, dz)));
  return __float_as_uint(d2);
}

__device__ __forceinline__ unsigned short tobf(float v) {
  return (unsigned short)((__float_as_uint(v) + 0x8000u) >> 16);
}

__device__ __forceinline__ void mfma_acc(f32x4& d, i32x4 a, i32x4 b) {
  asm("v_mfma_f32_16x16x32_bf16 %0, %1, %2, %0" : "+v"(d) : "v"(a), "v"(b));
}

// ---------------- K1: full scan -> clamped coarse hist + pairs ----------------
__global__ __launch_bounds__(256) void enc_hist_store(
    const float* __restrict__ nuc, const float* __restrict__ grid, int N,
    unsigned* __restrict__ hists, unsigned* __restrict__ cnt,
    uint2* __restrict__ pairs, int scap, unsigned* __restrict__ ghist2) {
  __shared__ unsigned lh[NB1];
  __shared__ unsigned s_cnt;
  int a = blockIdx.x / SLICES, s = blockIdx.x % SLICES;
  int tid = threadIdx.x, lane = tid & 63;
  if (tid < NB1) lh[tid] = 0;
  if (tid == 0) s_cnt = 0;
  { // zero this block's stripe of atom a's fine hist (written by K2 later)
    const int stripe = NB2 / SLICES;       // 16
    if (tid < stripe) ghist2[(size_t)a * NB2 + s * stripe + tid] = 0;
  }
  __syncthreads();

  float px = nuc[3*a+0], py = nuc[3*a+1], pz = nuc[3*a+2];
  uint2* seg = pairs + (size_t)blockIdx.x * scap;
  const float4* G4 = (const float4*)grid;
  int nq = N >> 2;
  int qper = (nq + SLICES - 1) / SLICES;
  int qlo = s * qper, qhi = min(nq, qlo + qper);

  for (int qi = qlo + tid; qi < qhi; qi += 256) {
    float4 A4 = G4[3*qi], B4 = G4[3*qi+1], C4 = G4[3*qi+2];
    float xs[4] = {A4.x, A4.w, B4.z, C4.y};
    float ys[4] = {A4.y, B4.x, B4.w, C4.z};
    float zs[4] = {A4.z, B4.y, C4.x, C4.w};
    unsigned bt[4];
    #pragma unroll
    for (int k = 0; k < 4; ++k) {
      bt[k] = d2bits(px, py, pz, xs[k], ys[k], zs[k]);
      if (bt[k] < CUT25) {
        int cb = (int)(bt[k] >> 18) - (int)CLAMP0;
        atomicAdd(&lh[cb > 0 ? cb : 0], 1u);
      }
    }
    #pragma unroll
    for (int k = 0; k < 4; ++k) {
      bool sel = bt[k] < CUT25;
      unsigned long long mm = __ballot(sel);
      if (mm) {
        int leader = __ffsll(mm) - 1;
        unsigned base = 0;
        if (lane == leader) base = atomicAdd(&s_cnt, (unsigned)__popcll(mm));
        base = __shfl(base, leader);
        if (sel) {
          unsigned pos = base + (unsigned)__popcll(mm & ((1ull << lane) - 1ull));
          if (pos < (unsigned)scap) seg[pos] = make_uint2(bt[k], (unsigned)(4*qi + k));
        }
      }
    }
  }
  if (s == SLICES - 1) {                   // scalar tail (N % 4 points)
    for (int i = 4*nq + tid; i < N; i += 256) {
      unsigned bits = d2bits(px, py, pz, grid[3*i+0], grid[3*i+1], grid[3*i+2]);
      bool sel = bits < CUT25;
      if (sel) {
        int cb = (int)(bits >> 18) - (int)CLAMP0;
        atomicAdd(&lh[cb > 0 ? cb : 0], 1u);
      }
      unsigned long long mm = __ballot(sel);
      if (mm) {
        int leader = __ffsll(mm) - 1;
        unsigned base = 0;
        if (lane == leader) base = atomicAdd(&s_cnt, (unsigned)__popcll(mm));
        base = __shfl(base, leader);
        if (sel) {
          unsigned pos = base + (unsigned)__popcll(mm & ((1ull << lane) - 1ull));
          if (pos < (unsigned)scap) seg[pos] = make_uint2(bits, (unsigned)i);
        }
      }
    }
  }
  __syncthreads();
  if (tid < NB1) hists[(size_t)blockIdx.x * NB1 + tid] = lh[tid];  // plain store
  if (tid == 0) cnt[blockIdx.x] = s_cnt;
}

// ---------------- K2: redundant coarse scan + fine hist (per segment) ----------------
__global__ __launch_bounds__(256) void enc_fine(
    const unsigned* __restrict__ hists, const unsigned* __restrict__ cnt,
    const uint2* __restrict__ pairs, int scap, unsigned T,
    unsigned* __restrict__ b1r, unsigned* __restrict__ r2r,
    unsigned* __restrict__ ghist2) {
  __shared__ unsigned lh[NB1];
  __shared__ unsigned s_bin, s_pre;
  int seg_id = blockIdx.x;
  int a = seg_id / SLICES, s = seg_id % SLICES;
  int tid = threadIdx.x;
  if (tid < NB1) {                         // sum the atom's 32 slice hists (32KB)
    unsigned acc = 0;
    const unsigned* base = hists + (size_t)a * SLICES * NB1 + tid;
    #pragma unroll 8
    for (int t = 0; t < SLICES; ++t) acc += base[(size_t)t * NB1];
    lh[tid] = acc;
  }
  if (tid == 0) { s_bin = NB1 - 1; s_pre = 0; }
  __syncthreads();
  if (tid < 64) {                          // parallel crossing-bin find
    int lane = tid, base = 4 * lane;
    unsigned h0 = lh[base], h1 = lh[base+1], h2 = lh[base+2], h3 = lh[base+3];
    unsigned ssum = h0 + h1 + h2 + h3;
    unsigned p = ssum;
    #pragma unroll
    for (int d = 1; d < 64; d <<= 1) {
      unsigned t = __shfl_up(p, d);
      if (lane >= d) p += t;
    }
    unsigned excl = p - ssum;
    if (excl < T && T <= p) {
      unsigned cum = excl;
      unsigned hh[4] = {h0, h1, h2, h3};
      #pragma unroll
      for (int k = 0; k < 4; ++k) {
        if (cum + hh[k] >= T) { s_bin = (unsigned)(base + k); s_pre = cum; break; }
        cum += hh[k];
      }
    }
  }
  __syncthreads();
  unsigned b1c = s_bin;
  if (s == 0 && tid == 0) { b1r[a] = s_bin; r2r[a] = T - s_pre; }

  unsigned tb1 = b1c + CLAMP0;
  int total = min((int)cnt[seg_id], scap);
  const uint2* seg = pairs + (size_t)seg_id * scap;
  unsigned* gh2 = ghist2 + (size_t)a * NB2;
  for (int i = tid; i < total; i += 256) {
    uint2 p = seg[i];
    unsigned cb = p.x >> 18;
    bool match = b1c ? (cb == tb1) : (cb <= CLAMP0);  // bin0 = clamped region
    if (match) atomicAdd(&gh2[(p.x >> 9) & (NB2 - 1)], 1u);
  }
}

// ---------------- K3: fine scan (2KB) + MFMA accumulation -> partials ----------------
__global__ __launch_bounds__(256, 4) void enc_accum(
    const float* __restrict__ nuc, const float* __restrict__ grid,
    const float* __restrict__ wv, const float* __restrict__ nv,
    const unsigned* __restrict__ b1r, const unsigned* __restrict__ r2r,
    const unsigned* __restrict__ ghist2, const unsigned* __restrict__ cnt,
    const uint2* __restrict__ pairs, int scap, float* __restrict__ pb) {
  __shared__ __align__(16) unsigned short lds[4][4608];  // per-wave 3456 A + 1152 B
  __shared__ unsigned lh2[NB2];
  __shared__ unsigned s_bin2;
  int seg_id = blockIdx.x / CHA, c = blockIdx.x % CHA;
  int a = seg_id / SLICES;
  int tid = threadIdx.x, lane = tid & 63, w = tid >> 6;
  unsigned short* SB = &lds[w][0];

  { // zero this wave's LDS region (covers A pad rows 33..47, B rows 9..15)
    i32x4 z = {0, 0, 0, 0};
    i32x4* zp = (i32x4*)SB;
    #pragma unroll
    for (int t = 0; t < 9; ++t) zp[lane + t * 64] = z;
  }
  { // stage atom's 512-bin fine hist (2KB)
    const unsigned* gh2 = ghist2 + (size_t)a * NB2;
    lh2[tid] = gh2[tid];
    lh2[tid + 256] = gh2[tid + 256];
  }
  if (tid == 0) s_bin2 = NB2 - 1;
  __syncthreads();
  unsigned R = r2r[a];
  if (tid < 64) {                          // two-level scan over 512 bins
    int lane2 = tid, base = 8 * lane2;
    unsigned hh[8], ssum = 0;
    #pragma unroll
    for (int k = 0; k < 8; ++k) { hh[k] = lh2[base + k]; ssum += hh[k]; }
    unsigned p = ssum;
    #pragma unroll
    for (int d = 1; d < 64; d <<= 1) {
      unsigned t = __shfl_up(p, d);
      if (lane2 >= d) p += t;
    }
    unsigned excl = p - ssum;
    if (excl < R && R <= p) {
      unsigned cum = excl;
      #pragma unroll
      for (int k = 0; k < 8; ++k) {
        if (cum + hh[k] >= R) { s_bin2 = (unsigned)(base + k); break; }
        cum += hh[k];
      }
    }
  }
  __syncthreads();
  unsigned thr = ((b1r[a] + CLAMP0) << 9) | s_bin2;   // select (bits>>9) <= thr

  float px = nuc[3*a+0], py = nuc[3*a+1], pz = nuc[3*a+2];
  int total = min((int)cnt[seg_id], scap);
  const uint2* lst = pairs + (size_t)seg_id * scap;

  f32x4 acc0 = {0,0,0,0}, acc1 = {0,0,0,0}, acc2 = {0,0,0,0};
  int m = lane & 15, q = lane >> 4;
  const float SQRT2 = 1.41421356237309515f;
  const float PIF   = 3.14159265358979323846f;
  const float S3    = 1.73205080756887729f;

  for (int jb = c * 256 + w * 64; jb < total; jb += CHA * 256) {
    int j = jb + lane;
    bool valid = j < total;
    uint2 pr = valid ? lst[j] : make_uint2(0xFFFFFFFFu, 0u);
    bool live = valid && ((pr.x >> 9) <= thr);   // stored => d2 < 25 => rn < 1
    unsigned gi = pr.y;
    if (live) {
      float gx = grid[3*gi+0], gy = grid[3*gi+1], gz = grid[3*gi+2];
      float dx = px - gx, dy = py - gy, dz = pz - gz;
      float d2 = __fmaf_rn(dx, dx, __fmaf_rn(dy, dy, dz * dz));
#if __has_builtin(__builtin_amdgcn_sqrtf)
      float rn = __builtin_amdgcn_sqrtf(d2) * 0.2f;
#else
      float rn = sqrtf(d2) * 0.2f;
#endif
      float x2 = rn * rn;
      float x6 = x2 * x2 * x2;
      float e  = __fmaf_rn(x6, __fmaf_rn(-21.f, x2, __fmaf_rn(48.f, rn, -28.f)), 1.f);
      float f  = SQRT2 * e;
      float nw = nv[gi] * wv[gi];
#if __has_builtin(__builtin_amdgcn_rcpf)
      float inv = 0.2f * __builtin_amdgcn_rcpf(rn + 1e-15f);
#else
      float inv = 0.2f / (rn + 1e-15f);
#endif
      float X = dx * inv, Y = dy * inv, Z = dz * inv;
      float r2 = __fmaf_rn(X, X, __fmaf_rn(Y, Y, Z * Z));
      // B rows: v[h] = nw * sh[h]
      SB[3456 + 0*72 + lane] = tobf(nw);
      SB[3456 + 1*72 + lane] = tobf(nw * Y);
      SB[3456 + 2*72 + lane] = tobf(nw * Z);
      SB[3456 + 3*72 + lane] = tobf(nw * X);
      SB[3456 + 4*72 + lane] = tobf(nw * S3 * X * Y);
      SB[3456 + 5*72 + lane] = tobf(nw * S3 * Y * Z);
      SB[3456 + 6*72 + lane] = tobf(nw * 0.5f * __fmaf_rn(3.f, Z * Z, -r2));
      SB[3456 + 7*72 + lane] = tobf(nw * S3 * X * Z);
      SB[3456 + 8*72 + lane] = tobf(nw * 0.5f * S3 * (X * X - Y * Y));
      // A rows: rbf[r] = sqrt2*e*[0.1, sin(k pi r), cos(k pi r)]
      // independent v_sin/v_cos per k: no serial chain (R12 lesson)
      float prr = PIF * rn;
      SB[0 * 72 + lane] = tobf(0.1f * f);
      #pragma unroll
      for (int k = 1; k <= 16; ++k) {
        float ang = (float)k * prr;
        SB[k * 72 + lane]        = tobf(f * __sinf(ang));
        SB[(16 + k) * 72 + lane] = tobf(f * __cosf(ang));
      }
    } else {
      // zero B column -> this point contributes nothing (A may be stale)
      #pragma unroll
      for (int h = 0; h < 9; ++h) SB[3456 + h * 72 + lane] = 0;
    }
    // MFMA: A[m=r][k=p], B[k=p][n=h]; lane m=l&15, k=8*(l>>4)+j (+32 per k-group)
    #pragma unroll
    for (int g = 0; g < 2; ++g) {
      int cb = 8 * q + 32 * g;
      i32x4 bf = *(const i32x4*)&SB[3456 + m * 72 + cb];
      i32x4 a0 = *(const i32x4*)&SB[(0  + m) * 72 + cb];
      mfma_acc(acc0, a0, bf);
      i32x4 a1 = *(const i32x4*)&SB[(16 + m) * 72 + cb];
      mfma_acc(acc1, a1, bf);
      i32x4 a2 = *(const i32x4*)&SB[(32 + m) * 72 + cb];
      mfma_acc(acc2, a2, bf);
    }
  }
  // MFMA -> VALU read hazard guard
  asm volatile("s_nop 7\n\ts_nop 7" : "+v"(acc0), "+v"(acc1), "+v"(acc2));

  // cross-wave reduction in LDS (wave-private regions)
  float* redw = (float*)&lds[w][0];
  if (m < 9) {
    #pragma unroll
    for (int t = 0; t < 4; ++t) {
      int row = 4 * q + t;                 // C/D: col=lane&15, row=(lane>>4)*4+t
      redw[(row +  0) * 9 + m] = acc0[t];
      redw[(row + 16) * 9 + m] = acc1[t];
      if (row + 32 < 33) redw[(row + 32) * 9 + m] = acc2[t];
    }
  }
  __syncthreads();
  float* pbb = pb + (size_t)blockIdx.x * PBSTR;
  for (int v = tid; v < 297; v += 256) {
    float s0 = ((const float*)&lds[0][0])[v] + ((const float*)&lds[1][0])[v];
    float s1 = ((const float*)&lds[2][0])[v] + ((const float*)&lds[3][0])[v];
    pbb[v] = s0 + s1;                      // plain store -- zero atomics
  }
}

// ---------------- K4: sum chunk partials -> out ----------------
__global__ __launch_bounds__(256) void enc_reduce(
    const float* __restrict__ pb, float* __restrict__ out, int nout) {
  int idx = blockIdx.x * 256 + threadIdx.x;
  if (idx >= nout) return;
  int a = idx / 297, v = idx - a * 297;
  const float* p = pb + (size_t)a * NCHUNK * PBSTR + v;
  float s = 0.f;
  #pragma unroll 8
  for (int k = 0; k < NCHUNK; ++k) s += p[(size_t)k * PBSTR];
  out[idx] = s;
}

extern "C" void kernel_launch(void* const* d_in, const int* in_sizes, int n_in,
                              void* d_out, int out_size, void* d_ws, size_t ws_size,
                              hipStream_t stream) {
  const float* nuc  = (const float*)d_in[0];
  // d_in[1] = atom_mask (unused by reference math)
  const float* grid = (const float*)d_in[2];
  const float* wts  = (const float*)d_in[3];
  const float* nn   = (const float*)d_in[4];
  int A = in_sizes[0] / 3;
  int N = in_sizes[2] / 3;
  long long t8 = (8LL * (long long)N) / (long long)A;
  unsigned T = (unsigned)(t8 < (long long)N ? t8 : (long long)N);

  // ws: [cnt A*SLICES][b1 A][r2 A][hists A*SLICES*NB1][ghist2 A*NB2]
  //     [pb A*SLICES*CHA*PBSTR floats][pairs uint2 ...]
  unsigned* ws     = (unsigned*)d_ws;
  unsigned* cnt    = ws;
  unsigned* b1r    = cnt + A * SLICES;
  unsigned* r2r    = b1r + A;
  unsigned* hists  = r2r + A;
  unsigned* ghist2 = hists + (size_t)A * SLICES * NB1;
  float*    pb     = (float*)(ghist2 + (size_t)A * NB2);
  uint2*    pairs  = (uint2*)(pb + (size_t)A * SLICES * CHA * PBSTR);

  // per-slice quad range bounds the stored count -> overflow impossible
  int nq   = N >> 2;
  int qper = (nq + SLICES - 1) / SLICES;
  int SCAP = qper * 4 + 4;
  {
    long long head  = (long long)(((unsigned*)pairs) - ws);    // dwords
    long long avail = (long long)(ws_size / 4) - head;         // dwords
    long long need  = 2LL * SCAP * A * SLICES;                 // uint2 = 2 dwords
    if (avail > 0 && need > avail) SCAP = (int)(avail / (2LL * A * SLICES));
  }
  float* out = (float*)d_out;
  int nout = A * 297;

  enc_hist_store<<<A * SLICES,         256, 0, stream>>>(nuc, grid, N, hists, cnt,
                                                         pairs, SCAP, ghist2);
  enc_fine      <<<A * SLICES,         256, 0, stream>>>(hists, cnt, pairs, SCAP, T,
                                                         b1r, r2r, ghist2);
  enc_accum     <<<A * SLICES * CHA,   256, 0, stream>>>(nuc, grid, wts, nn, b1r, r2r,
                                                         ghist2, cnt, pairs, SCAP, pb);
  enc_reduce    <<<(nout + 255) / 256, 256, 0, stream>>>(pb, out, nout);
}

// Round 14
// 64.831 us; speedup vs baseline: 1.2151x; 1.2151x over previous
//
#include <hip/hip_runtime.h>
#include <hip/hip_fp16.h>

// Encoder: per-atom top-T nearest grid points -> sum_t rbf[33] (x) (sh[9]*n*w)
// R13 lessons: (1) sincos recurrence BEATS independent native sin/cos (revert);
// (2) accum is stall-bound on its 5 scattered gathers per point -> store a
// 16B self-contained record (bits, f16 dx/dy/dz, f32 nw) in hist_store where
// all of it is already computed/streamed; accum reads ONE coalesced uint4.
// 4 dispatches:
// K1 hist_store: full scan; 256-bin clamped coarse hist; 16B record append
// K2 fine      : redundant coarse scan -> b1; fine hist -> ghist2[a][512]
// K3 accum     : stage 2KB fine hist, scan -> thr; filter records, bf16 MFMA,
//                LDS cross-wave reduce, one plain 297-float store per block
// K4 reduce    : sum 64 chunk-partials per atom -> out

typedef float f32x4 __attribute__((ext_vector_type(4)));
typedef int   i32x4 __attribute__((ext_vector_type(4)));

#define SLICES 32
#define NB1    256           // coarse bins (clamped)
#define NB2    512           // fine bins: bits[17:9] within crossing bin
#define CLAMP0 4000u         // bits>>18 below this (d2<~0.25) -> bin 0
#define CHA    2             // accum chunks per segment
#define NCHUNK (SLICES * CHA)
#define PBSTR  304           // partials row stride
#define CUT25  0x41C80000u   // __float_as_uint(25.0f) == CUTOFF^2 bits

__device__ __forceinline__ unsigned short tobf(float v) {
  return (unsigned short)((__float_as_uint(v) + 0x8000u) >> 16);
}

__device__ __forceinline__ unsigned pack2h(float a, float b) {
  __half2 h = __floats2half2_rn(a, b);
  return *reinterpret_cast<unsigned*>(&h);
}

__device__ __forceinline__ void mfma_acc(f32x4& d, i32x4 a, i32x4 b) {
  asm("v_mfma_f32_16x16x32_bf16 %0, %1, %2, %0" : "+v"(d) : "v"(a), "v"(b));
}

// ---------------- K1: full scan -> clamped coarse hist + 16B records ----------------
__global__ __launch_bounds__(256) void enc_hist_store(
    const float* __restrict__ nuc, const float* __restrict__ grid,
    const float* __restrict__ wv, const float* __restrict__ nv, int N,
    unsigned* __restrict__ hists, unsigned* __restrict__ cnt,
    uint4* __restrict__ recs, int scap, unsigned* __restrict__ ghist2) {
  __shared__ unsigned lh[NB1];
  __shared__ unsigned s_cnt;
  int a = blockIdx.x / SLICES, s = blockIdx.x % SLICES;
  int tid = threadIdx.x, lane = tid & 63;
  if (tid < NB1) lh[tid] = 0;
  if (tid == 0) s_cnt = 0;
  { // zero this block's stripe of atom a's fine hist (written by K2 later)
    const int stripe = NB2 / SLICES;       // 16
    if (tid < stripe) ghist2[(size_t)a * NB2 + s * stripe + tid] = 0;
  }
  __syncthreads();

  float px = nuc[3*a+0], py = nuc[3*a+1], pz = nuc[3*a+2];
  uint4* seg = recs + (size_t)blockIdx.x * scap;
  const float4* G4 = (const float4*)grid;
  const float4* W4 = (const float4*)wv;
  const float4* V4 = (const float4*)nv;
  int nq = N >> 2;
  int qper = (nq + SLICES - 1) / SLICES;
  int qlo = s * qper, qhi = min(nq, qlo + qper);

  for (int qi = qlo + tid; qi < qhi; qi += 256) {
    float4 A4 = G4[3*qi], B4 = G4[3*qi+1], C4 = G4[3*qi+2];
    float4 w4 = W4[qi], v4 = V4[qi];
    float xs[4] = {A4.x, A4.w, B4.z, C4.y};
    float ys[4] = {A4.y, B4.x, B4.w, C4.z};
    float zs[4] = {A4.z, B4.y, C4.x, C4.w};
    float nws[4] = {v4.x * w4.x, v4.y * w4.y, v4.z * w4.z, v4.w * w4.w};
    float dxs[4], dys[4], dzs[4];
    unsigned bt[4];
    #pragma unroll
    for (int k = 0; k < 4; ++k) {
      float dx = px - xs[k], dy = py - ys[k], dz = pz - zs[k];
      dxs[k] = dx; dys[k] = dy; dzs[k] = dz;
      float d2 = __fmaf_rn(dx, dx, __fmaf_rn(dy, dy, __fmul_rn(dz, dz)));
      bt[k] = __float_as_uint(d2);
      if (bt[k] < CUT25) {
        int cb = (int)(bt[k] >> 18) - (int)CLAMP0;
        atomicAdd(&lh[cb > 0 ? cb : 0], 1u);
      }
    }
    #pragma unroll
    for (int k = 0; k < 4; ++k) {
      bool sel = bt[k] < CUT25;                    // envelope != 0 only here
      unsigned long long mm = __ballot(sel);
      if (mm) {
        int leader = __ffsll(mm) - 1;
        unsigned base = 0;
        if (lane == leader) base = atomicAdd(&s_cnt, (unsigned)__popcll(mm));
        base = __shfl(base, leader);
        if (sel) {
          unsigned pos = base + (unsigned)__popcll(mm & ((1ull << lane) - 1ull));
          if (pos < (unsigned)scap) {
            uint4 r;
            r.x = bt[k];
            r.y = pack2h(dxs[k], dys[k]);
            r.z = pack2h(dzs[k], 0.f);
            r.w = __float_as_uint(nws[k]);
            seg[pos] = r;
          }
        }
      }
    }
  }
  if (s == SLICES - 1) {                   // scalar tail (N % 4 points)
    for (int i = 4*nq + tid; i < N; i += 256) {
      float dx = px - grid[3*i+0], dy = py - grid[3*i+1], dz = pz - grid[3*i+2];
      float d2 = __fmaf_rn(dx, dx, __fmaf_rn(dy, dy, __fmul_rn(dz, dz)));
      unsigned bits = __float_as_uint(d2);
      bool sel = bits < CUT25;
      if (sel) {
        int cb = (int)(bits >> 18) - (int)CLAMP0;
        atomicAdd(&lh[cb > 0 ? cb : 0], 1u);
      }
      unsigned long long mm = __ballot(sel);
      if (mm) {
        int leader = __ffsll(mm) - 1;
        unsigned base = 0;
        if (lane == leader) base = atomicAdd(&s_cnt, (unsigned)__popcll(mm));
        base = __shfl(base, leader);
        if (sel) {
          unsigned pos = base + (unsigned)__popcll(mm & ((1ull << lane) - 1ull));
          if (pos < (unsigned)scap) {
            uint4 r;
            r.x = bits;
            r.y = pack2h(dx, dy);
            r.z = pack2h(dz, 0.f);
            r.w = __float_as_uint(nv[i] * wv[i]);
            seg[pos] = r;
          }
        }
      }
    }
  }
  __syncthreads();
  if (tid < NB1) hists[(size_t)blockIdx.x * NB1 + tid] = lh[tid];  // plain store
  if (tid == 0) cnt[blockIdx.x] = s_cnt;
}

// ---------------- K2: redundant coarse scan + fine hist (per segment) ----------------
__global__ __launch_bounds__(256) void enc_fine(
    const unsigned* __restrict__ hists, const unsigned* __restrict__ cnt,
    const uint4* __restrict__ recs, int scap, unsigned T,
    unsigned* __restrict__ b1r, unsigned* __restrict__ r2r,
    unsigned* __restrict__ ghist2) {
  __shared__ unsigned lh[NB1];
  __shared__ unsigned s_bin, s_pre;
  int seg_id = blockIdx.x;
  int a = seg_id / SLICES, s = seg_id % SLICES;
  int tid = threadIdx.x;
  if (tid < NB1) {                         // sum the atom's 32 slice hists (32KB)
    unsigned acc = 0;
    const unsigned* base = hists + (size_t)a * SLICES * NB1 + tid;
    #pragma unroll 8
    for (int t = 0; t < SLICES; ++t) acc += base[(size_t)t * NB1];
    lh[tid] = acc;
  }
  if (tid == 0) { s_bin = NB1 - 1; s_pre = 0; }
  __syncthreads();
  if (tid < 64) {                          // parallel crossing-bin find
    int lane = tid, base = 4 * lane;
    unsigned h0 = lh[base], h1 = lh[base+1], h2 = lh[base+2], h3 = lh[base+3];
    unsigned ssum = h0 + h1 + h2 + h3;
    unsigned p = ssum;
    #pragma unroll
    for (int d = 1; d < 64; d <<= 1) {
      unsigned t = __shfl_up(p, d);
      if (lane >= d) p += t;
    }
    unsigned excl = p - ssum;
    if (excl < T && T <= p) {
      unsigned cum = excl;
      unsigned hh[4] = {h0, h1, h2, h3};
      #pragma unroll
      for (int k = 0; k < 4; ++k) {
        if (cum + hh[k] >= T) { s_bin = (unsigned)(base + k); s_pre = cum; break; }
        cum += hh[k];
      }
    }
  }
  __syncthreads();
  unsigned b1c = s_bin;
  if (s == 0 && tid == 0) { b1r[a] = s_bin; r2r[a] = T - s_pre; }

  unsigned tb1 = b1c + CLAMP0;
  int total = min((int)cnt[seg_id], scap);
  const unsigned* segb = (const unsigned*)(recs + (size_t)seg_id * scap);
  unsigned* gh2 = ghist2 + (size_t)a * NB2;
  for (int i = tid; i < total; i += 256) {
    unsigned bits = segb[4 * i];           // rec.x only
    unsigned cb = bits >> 18;
    bool match = b1c ? (cb == tb1) : (cb <= CLAMP0);  // bin0 = clamped region
    if (match) atomicAdd(&gh2[(bits >> 9) & (NB2 - 1)], 1u);
  }
}

// ---------------- K3: fine scan (2KB) + MFMA accumulation -> partials ----------------
__global__ __launch_bounds__(256, 4) void enc_accum(
    const unsigned* __restrict__ b1r, const unsigned* __restrict__ r2r,
    const unsigned* __restrict__ ghist2, const unsigned* __restrict__ cnt,
    const uint4* __restrict__ recs, int scap, float* __restrict__ pb) {
  __shared__ __align__(16) unsigned short lds[4][4608];  // per-wave 3456 A + 1152 B
  __shared__ unsigned lh2[NB2];
  __shared__ unsigned s_bin2;
  int seg_id = blockIdx.x / CHA, c = blockIdx.x % CHA;
  int a = seg_id / SLICES;
  int tid = threadIdx.x, lane = tid & 63, w = tid >> 6;
  unsigned short* SB = &lds[w][0];

  { // zero this wave's LDS region (covers A pad rows 33..47, B rows 9..15)
    i32x4 z = {0, 0, 0, 0};
    i32x4* zp = (i32x4*)SB;
    #pragma unroll
    for (int t = 0; t < 9; ++t) zp[lane + t * 64] = z;
  }
  { // stage atom's 512-bin fine hist (2KB)
    const unsigned* gh2 = ghist2 + (size_t)a * NB2;
    lh2[tid] = gh2[tid];
    lh2[tid + 256] = gh2[tid + 256];
  }
  if (tid == 0) s_bin2 = NB2 - 1;
  __syncthreads();
  unsigned R = r2r[a];
  if (tid < 64) {                          // two-level scan over 512 bins
    int lane2 = tid, base = 8 * lane2;
    unsigned hh[8], ssum = 0;
    #pragma unroll
    for (int k = 0; k < 8; ++k) { hh[k] = lh2[base + k]; ssum += hh[k]; }
    unsigned p = ssum;
    #pragma unroll
    for (int d = 1; d < 64; d <<= 1) {
      unsigned t = __shfl_up(p, d);
      if (lane2 >= d) p += t;
    }
    unsigned excl = p - ssum;
    if (excl < R && R <= p) {
      unsigned cum = excl;
      #pragma unroll
      for (int k = 0; k < 8; ++k) {
        if (cum + hh[k] >= R) { s_bin2 = (unsigned)(base + k); break; }
        cum += hh[k];
      }
    }
  }
  __syncthreads();
  unsigned thr = ((b1r[a] + CLAMP0) << 9) | s_bin2;   // select (bits>>9) <= thr

  int total = min((int)cnt[seg_id], scap);
  const uint4* lst = recs + (size_t)seg_id * scap;

  f32x4 acc0 = {0,0,0,0}, acc1 = {0,0,0,0}, acc2 = {0,0,0,0};
  int m = lane & 15, q = lane >> 4;
  const float SQRT2 = 1.41421356237309515f;
  const float PIF   = 3.14159265358979323846f;
  const float S3    = 1.73205080756887729f;

  for (int jb = c * 256 + w * 64; jb < total; jb += CHA * 256) {
    int j = jb + lane;
    bool valid = j < total;
    uint4 pr;
    if (valid) pr = lst[j]; else pr.x = 0xFFFFFFFFu;
    bool live = valid && ((pr.x >> 9) <= thr);   // stored => d2 < 25 => rn < 1
    if (live) {
      // decode record: exact d2 bits + f16 directions + f32 nw (no gathers!)
      float d2 = __uint_as_float(pr.x);
      __half2 hxy = *reinterpret_cast<const __half2*>(&pr.y);
      __half2 hz2 = *reinterpret_cast<const __half2*>(&pr.z);
      float dx = __low2float(hxy), dy = __high2float(hxy), dz = __low2float(hz2);
      float nw = __uint_as_float(pr.w);
#if __has_builtin(__builtin_amdgcn_sqrtf)
      float rn = __builtin_amdgcn_sqrtf(d2) * 0.2f;
#else
      float rn = sqrtf(d2) * 0.2f;
#endif
      float x2 = rn * rn;
      float x6 = x2 * x2 * x2;
      float e  = __fmaf_rn(x6, __fmaf_rn(-21.f, x2, __fmaf_rn(48.f, rn, -28.f)), 1.f);
      float f  = SQRT2 * e;
#if __has_builtin(__builtin_amdgcn_rcpf)
      float inv = 0.2f * __builtin_amdgcn_rcpf(rn + 1e-15f);
#else
      float inv = 0.2f / (rn + 1e-15f);
#endif
      float X = dx * inv, Y = dy * inv, Z = dz * inv;
      float r2 = __fmaf_rn(X, X, __fmaf_rn(Y, Y, Z * Z));
      // B rows: v[h] = nw * sh[h]
      SB[3456 + 0*72 + lane] = tobf(nw);
      SB[3456 + 1*72 + lane] = tobf(nw * Y);
      SB[3456 + 2*72 + lane] = tobf(nw * Z);
      SB[3456 + 3*72 + lane] = tobf(nw * X);
      SB[3456 + 4*72 + lane] = tobf(nw * S3 * X * Y);
      SB[3456 + 5*72 + lane] = tobf(nw * S3 * Y * Z);
      SB[3456 + 6*72 + lane] = tobf(nw * 0.5f * __fmaf_rn(3.f, Z * Z, -r2));
      SB[3456 + 7*72 + lane] = tobf(nw * S3 * X * Z);
      SB[3456 + 8*72 + lane] = tobf(nw * 0.5f * S3 * (X * X - Y * Y));
      // A rows: rbf[r] = sqrt2*e*[0.1, sin(k pi r), cos(k pi r)]
      // recurrence (R13 lesson: beats independent native sin/cos)
      float s1, c1;
      __sincosf(PIF * rn, &s1, &c1);
      SB[0 * 72 + lane]  = tobf(0.1f * f);
      float sk = s1, ck = c1;
      SB[1 * 72 + lane]  = tobf(f * sk);
      SB[17 * 72 + lane] = tobf(f * ck);
      #pragma unroll
      for (int k = 2; k <= 16; ++k) {
        float sn = __fmaf_rn(sk, c1, ck * s1);
        float cn = __fmaf_rn(ck, c1, -(sk * s1));
        sk = sn; ck = cn;
        SB[k * 72 + lane]        = tobf(f * sk);
        SB[(16 + k) * 72 + lane] = tobf(f * ck);
      }
    } else {
      // zero B column -> this point contributes nothing (A may be stale)
      #pragma unroll
      for (int h = 0; h < 9; ++h) SB[3456 + h * 72 + lane] = 0;
    }
    // MFMA: A[m=r][k=p], B[k=p][n=h]; lane m=l&15, k=8*(l>>4)+j (+32 per k-group)
    #pragma unroll
    for (int g = 0; g < 2; ++g) {
      int cb = 8 * q + 32 * g;
      i32x4 bf = *(const i32x4*)&SB[3456 + m * 72 + cb];
      i32x4 a0 = *(const i32x4*)&SB[(0  + m) * 72 + cb];
      mfma_acc(acc0, a0, bf);
      i32x4 a1 = *(const i32x4*)&SB[(16 + m) * 72 + cb];
      mfma_acc(acc1, a1, bf);
      i32x4 a2 = *(const i32x4*)&SB[(32 + m) * 72 + cb];
      mfma_acc(acc2, a2, bf);
    }
  }
  // MFMA -> VALU read hazard guard
  asm volatile("s_nop 7\n\ts_nop 7" : "+v"(acc0), "+v"(acc1), "+v"(acc2));

  // cross-wave reduction in LDS (wave-private regions)
  float* redw = (float*)&lds[w][0];
  if (m < 9) {
    #pragma unroll
    for (int t = 0; t < 4; ++t) {
      int row = 4 * q + t;                 // C/D: col=lane&15, row=(lane>>4)*4+t
      redw[(row +  0) * 9 + m] = acc0[t];
      redw[(row + 16) * 9 + m] = acc1[t];
      if (row + 32 < 33) redw[(row + 32) * 9 + m] = acc2[t];
    }
  }
  __syncthreads();
  float* pbb = pb + (size_t)blockIdx.x * PBSTR;
  for (int v = tid; v < 297; v += 256) {
    float s0 = ((const float*)&lds[0][0])[v] + ((const float*)&lds[1][0])[v];
    float s1 = ((const float*)&lds[2][0])[v] + ((const float*)&lds[3][0])[v];
    pbb[v] = s0 + s1;                      // plain store -- zero atomics
  }
}

// ---------------- K4: sum chunk partials -> out ----------------
__global__ __launch_bounds__(256) void enc_reduce(
    const float* __restrict__ pb, float* __restrict__ out, int nout) {
  int idx = blockIdx.x * 256 + threadIdx.x;
  if (idx >= nout) return;
  int a = idx / 297, v = idx - a * 297;
  const float* p = pb + (size_t)a * NCHUNK * PBSTR + v;
  float s = 0.f;
  #pragma unroll 8
  for (int k = 0; k < NCHUNK; ++k) s += p[(size_t)k * PBSTR];
  out[idx] = s;
}

extern "C" void kernel_launch(void* const* d_in, const int* in_sizes, int n_in,
                              void* d_out, int out_size, void* d_ws, size_t ws_size,
                              hipStream_t stream) {
  const float* nuc  = (const float*)d_in[0];
  // d_in[1] = atom_mask (unused by reference math)
  const float* grid = (const float*)d_in[2];
  const float* wts  = (const float*)d_in[3];
  const float* nn   = (const float*)d_in[4];
  int A = in_sizes[0] / 3;
  int N = in_sizes[2] / 3;
  long long t8 = (8LL * (long long)N) / (long long)A;
  unsigned T = (unsigned)(t8 < (long long)N ? t8 : (long long)N);

  // ws: [cnt A*SLICES][b1 A][r2 A][hists A*SLICES*NB1][ghist2 A*NB2]
  //     [pb A*SLICES*CHA*PBSTR floats][recs uint4 ...]
  unsigned* ws     = (unsigned*)d_ws;
  unsigned* cnt    = ws;
  unsigned* b1r    = cnt + A * SLICES;
  unsigned* r2r    = b1r + A;
  unsigned* hists  = r2r + A;
  unsigned* ghist2 = hists + (size_t)A * SLICES * NB1;
  float*    pb     = (float*)(ghist2 + (size_t)A * NB2);
  uint4*    recs   = (uint4*)(pb + (size_t)A * SLICES * CHA * PBSTR);

  // per-slice quad range bounds the stored count -> overflow impossible
  int nq   = N >> 2;
  int qper = (nq + SLICES - 1) / SLICES;
  int SCAP = qper * 4 + 4;
  {
    long long head  = (long long)(((unsigned*)recs) - ws);     // dwords
    long long avail = (long long)(ws_size / 4) - head;         // dwords
    long long need  = 4LL * SCAP * A * SLICES;                 // uint4 = 4 dwords
    if (avail > 0 && need > avail) SCAP = (int)(avail / (4LL * A * SLICES));
  }
  float* out = (float*)d_out;
  int nout = A * 297;

  enc_hist_store<<<A * SLICES,         256, 0, stream>>>(nuc, grid, wts, nn, N, hists,
                                                         cnt, recs, SCAP, ghist2);
  enc_fine      <<<A * SLICES,         256, 0, stream>>>(hists, cnt, recs, SCAP, T,
                                                         b1r, r2r, ghist2);
  enc_accum     <<<A * SLICES * CHA,   256, 0, stream>>>(b1r, r2r, ghist2, cnt,
                                                         recs, SCAP, pb);
  enc_reduce    <<<(nout + 255) / 256, 256, 0, stream>>>(pb, out, nout);
}

// Round 15
// 63.814 us; speedup vs baseline: 1.2345x; 1.0159x over previous
//
#include <hip/hip_runtime.h>
#include <hip/hip_fp16.h>

// Encoder: per-atom top-T nearest grid points -> sum_t rbf[33] (x) (sh[9]*n*w)
// R14 lesson: accum is per-block-fixed-cost bound (2 main-loop iters/wave vs
// ~2k-cycle prologue; 4 blocks/CU LDS cap). Remove prologue, raise occupancy.
// 6 dispatches (all small; boundaries ~0.5us each):
// K1 hist_store: full scan; 256-bin clamped coarse hist; append bits(4B) +
//                payload(8B: f16 dx,dy,dz,nw); zero ghist2 stripe
// K2 scan1     : per-atom: sum 32x256-bin hists -> b1, residual R2
// K3 fine      : fine hist bits[17:9] of crossing-bin points (bits-only read)
// K4 scan2     : per-atom: scan 512-bin fine hist -> thr[a]
// K5 accum     : thr = scalar load; filter, features, bf16 MFMA, LDS reduce,
//                one plain 297-float store per block. 49-row/wave LDS (28KB,
//                5 blocks/CU): A rows 33..47 were padding -- MFMA reads past
//                row 32 feed only discarded C rows.
// K6 reduce    : sum 64 chunk-partials per atom -> out

typedef float f32x4 __attribute__((ext_vector_type(4)));
typedef int   i32x4 __attribute__((ext_vector_type(4)));

#define SLICES 32
#define NB1    256           // coarse bins (clamped)
#define NB2    512           // fine bins: bits[17:9] within crossing bin
#define CLAMP0 4000u         // bits>>18 below this (d2<~0.25) -> bin 0
#define CHA    2             // accum chunks per segment
#define NCHUNK (SLICES * CHA)
#define PBSTR  304           // partials row stride
#define CUT25  0x41C80000u   // __float_as_uint(25.0f) == CUTOFF^2 bits
#define WROWS  49            // accum: 33 A rows + 16 B rows per wave
#define BBASE  (33 * 72)     // B region offset (shorts)

__device__ __forceinline__ unsigned short tobf(float v) {
  return (unsigned short)((__float_as_uint(v) + 0x8000u) >> 16);
}

__device__ __forceinline__ unsigned pack2h(float a, float b) {
  __half2 h = __floats2half2_rn(a, b);
  return *reinterpret_cast<unsigned*>(&h);
}

__device__ __forceinline__ void mfma_acc(f32x4& d, i32x4 a, i32x4 b) {
  asm("v_mfma_f32_16x16x32_bf16 %0, %1, %2, %0" : "+v"(d) : "v"(a), "v"(b));
}

// ---------------- K1: full scan -> coarse hist + bits/payload append ----------------
__global__ __launch_bounds__(256) void enc_hist_store(
    const float* __restrict__ nuc, const float* __restrict__ grid,
    const float* __restrict__ wv, const float* __restrict__ nv, int N,
    unsigned* __restrict__ hists, unsigned* __restrict__ cnt,
    unsigned* __restrict__ bitsArr, uint2* __restrict__ pay, int scap,
    unsigned* __restrict__ ghist2) {
  __shared__ unsigned lh[NB1];
  __shared__ unsigned s_cnt;
  int a = blockIdx.x / SLICES, s = blockIdx.x % SLICES;
  int tid = threadIdx.x, lane = tid & 63;
  if (tid < NB1) lh[tid] = 0;
  if (tid == 0) s_cnt = 0;
  { // zero this block's stripe of atom a's fine hist (written by K3 later)
    const int stripe = NB2 / SLICES;       // 16
    if (tid < stripe) ghist2[(size_t)a * NB2 + s * stripe + tid] = 0;
  }
  __syncthreads();

  float px = nuc[3*a+0], py = nuc[3*a+1], pz = nuc[3*a+2];
  unsigned* segb = bitsArr + (size_t)blockIdx.x * scap;
  uint2*    segp = pay     + (size_t)blockIdx.x * scap;
  const float4* G4 = (const float4*)grid;
  const float4* W4 = (const float4*)wv;
  const float4* V4 = (const float4*)nv;
  int nq = N >> 2;
  int qper = (nq + SLICES - 1) / SLICES;
  int qlo = s * qper, qhi = min(nq, qlo + qper);

  for (int qi = qlo + tid; qi < qhi; qi += 256) {
    float4 A4 = G4[3*qi], B4 = G4[3*qi+1], C4 = G4[3*qi+2];
    float4 w4 = W4[qi], v4 = V4[qi];
    float xs[4] = {A4.x, A4.w, B4.z, C4.y};
    float ys[4] = {A4.y, B4.x, B4.w, C4.z};
    float zs[4] = {A4.z, B4.y, C4.x, C4.w};
    float nws[4] = {v4.x * w4.x, v4.y * w4.y, v4.z * w4.z, v4.w * w4.w};
    float dxs[4], dys[4], dzs[4];
    unsigned bt[4];
    #pragma unroll
    for (int k = 0; k < 4; ++k) {
      float dx = px - xs[k], dy = py - ys[k], dz = pz - zs[k];
      dxs[k] = dx; dys[k] = dy; dzs[k] = dz;
      float d2 = __fmaf_rn(dx, dx, __fmaf_rn(dy, dy, __fmul_rn(dz, dz)));
      bt[k] = __float_as_uint(d2);
      if (bt[k] < CUT25) {
        int cb = (int)(bt[k] >> 18) - (int)CLAMP0;
        atomicAdd(&lh[cb > 0 ? cb : 0], 1u);
      }
    }
    #pragma unroll
    for (int k = 0; k < 4; ++k) {
      bool sel = bt[k] < CUT25;                    // envelope != 0 only here
      unsigned long long mm = __ballot(sel);
      if (mm) {
        int leader = __ffsll(mm) - 1;
        unsigned base = 0;
        if (lane == leader) base = atomicAdd(&s_cnt, (unsigned)__popcll(mm));
        base = __shfl(base, leader);
        if (sel) {
          unsigned pos = base + (unsigned)__popcll(mm & ((1ull << lane) - 1ull));
          if (pos < (unsigned)scap) {
            segb[pos] = bt[k];
            segp[pos] = make_uint2(pack2h(dxs[k], dys[k]), pack2h(dzs[k], nws[k]));
          }
        }
      }
    }
  }
  if (s == SLICES - 1) {                   // scalar tail (N % 4 points)
    for (int i = 4*nq + tid; i < N; i += 256) {
      float dx = px - grid[3*i+0], dy = py - grid[3*i+1], dz = pz - grid[3*i+2];
      float d2 = __fmaf_rn(dx, dx, __fmaf_rn(dy, dy, __fmul_rn(dz, dz)));
      unsigned bits = __float_as_uint(d2);
      bool sel = bits < CUT25;
      if (sel) {
        int cb = (int)(bits >> 18) - (int)CLAMP0;
        atomicAdd(&lh[cb > 0 ? cb : 0], 1u);
      }
      unsigned long long mm = __ballot(sel);
      if (mm) {
        int leader = __ffsll(mm) - 1;
        unsigned base = 0;
        if (lane == leader) base = atomicAdd(&s_cnt, (unsigned)__popcll(mm));
        base = __shfl(base, leader);
        if (sel) {
          unsigned pos = base + (unsigned)__popcll(mm & ((1ull << lane) - 1ull));
          if (pos < (unsigned)scap) {
            segb[pos] = bits;
            segp[pos] = make_uint2(pack2h(dx, dy), pack2h(dz, nv[i] * wv[i]));
          }
        }
      }
    }
  }
  __syncthreads();
  if (tid < NB1) hists[(size_t)blockIdx.x * NB1 + tid] = lh[tid];  // plain store
  if (tid == 0) cnt[blockIdx.x] = s_cnt;
}

// ---------------- K2: per-atom coarse scan -> b1, R2 ----------------
__global__ __launch_bounds__(256) void enc_scan1(
    const unsigned* __restrict__ hists, unsigned T,
    unsigned* __restrict__ b1r, unsigned* __restrict__ r2r) {
  __shared__ unsigned lh[NB1];
  __shared__ unsigned s_bin, s_pre;
  int a = blockIdx.x, tid = threadIdx.x;
  if (tid < NB1) {
    unsigned acc = 0;
    const unsigned* base = hists + (size_t)a * SLICES * NB1 + tid;
    #pragma unroll 8
    for (int t = 0; t < SLICES; ++t) acc += base[(size_t)t * NB1];
    lh[tid] = acc;
  }
  if (tid == 0) { s_bin = NB1 - 1; s_pre = 0; }
  __syncthreads();
  if (tid < 64) {
    int lane = tid, base = 4 * lane;
    unsigned h0 = lh[base], h1 = lh[base+1], h2 = lh[base+2], h3 = lh[base+3];
    unsigned ssum = h0 + h1 + h2 + h3;
    unsigned p = ssum;
    #pragma unroll
    for (int d = 1; d < 64; d <<= 1) {
      unsigned t = __shfl_up(p, d);
      if (lane >= d) p += t;
    }
    unsigned excl = p - ssum;
    if (excl < T && T <= p) {              // unique crossing lane
      unsigned cum = excl;
      unsigned hh[4] = {h0, h1, h2, h3};
      #pragma unroll
      for (int k = 0; k < 4; ++k) {
        if (cum + hh[k] >= T) { s_bin = (unsigned)(base + k); s_pre = cum; break; }
        cum += hh[k];
      }
    }
  }
  __syncthreads();
  if (tid == 0) { b1r[a] = s_bin; r2r[a] = T - s_pre; }
}

// ---------------- K3: fine hist of crossing-bin points (bits-only) ----------------
__global__ __launch_bounds__(256) void enc_fine(
    const unsigned* __restrict__ b1r, const unsigned* __restrict__ cnt,
    const unsigned* __restrict__ bitsArr, int scap,
    unsigned* __restrict__ ghist2) {
  int seg_id = blockIdx.x;
  int a = seg_id / SLICES;
  unsigned b1c = b1r[a];
  unsigned tb1 = b1c + CLAMP0;
  int total = min((int)cnt[seg_id], scap);
  const unsigned* segb = bitsArr + (size_t)seg_id * scap;
  unsigned* gh2 = ghist2 + (size_t)a * NB2;
  for (int i = threadIdx.x; i < total; i += 256) {
    unsigned bits = segb[i];
    unsigned cb = bits >> 18;
    bool match = b1c ? (cb == tb1) : (cb <= CLAMP0);  // bin0 = clamped region
    if (match) atomicAdd(&gh2[(bits >> 9) & (NB2 - 1)], 1u);
  }
}

// ---------------- K4: per-atom fine scan -> thr ----------------
__global__ __launch_bounds__(256) void enc_scan2(
    const unsigned* __restrict__ ghist2, const unsigned* __restrict__ b1r,
    const unsigned* __restrict__ r2r, unsigned* __restrict__ thr) {
  __shared__ unsigned lh2[NB2];
  __shared__ unsigned s_bin2;
  int a = blockIdx.x, tid = threadIdx.x;
  const unsigned* gh2 = ghist2 + (size_t)a * NB2;
  lh2[tid] = gh2[tid];
  lh2[tid + 256] = gh2[tid + 256];
  if (tid == 0) s_bin2 = NB2 - 1;
  __syncthreads();
  unsigned R = r2r[a];
  if (tid < 64) {                          // two-level scan over 512 bins
    int lane = tid, base = 8 * lane;
    unsigned hh[8], ssum = 0;
    #pragma unroll
    for (int k = 0; k < 8; ++k) { hh[k] = lh2[base + k]; ssum += hh[k]; }
    unsigned p = ssum;
    #pragma unroll
    for (int d = 1; d < 64; d <<= 1) {
      unsigned t = __shfl_up(p, d);
      if (lane >= d) p += t;
    }
    unsigned excl = p - ssum;
    if (excl < R && R <= p) {
      unsigned cum = excl;
      #pragma unroll
      for (int k = 0; k < 8; ++k) {
        if (cum + hh[k] >= R) { s_bin2 = (unsigned)(base + k); break; }
        cum += hh[k];
      }
    }
  }
  __syncthreads();
  if (tid == 0) thr[a] = ((b1r[a] + CLAMP0) << 9) | s_bin2;  // (bits>>9) <= thr
}

// ---------------- K5: MFMA accumulation -> per-block partials ----------------
__global__ __launch_bounds__(256, 5) void enc_accum(
    const unsigned* __restrict__ thrv, const unsigned* __restrict__ cnt,
    const unsigned* __restrict__ bitsArr, const uint2* __restrict__ pay,
    int scap, float* __restrict__ pb) {
  // per-wave 49-row x 72-short region: A rows 0..32, B rows 33..48.
  // MFMA a2 reads rows 32..47 (rows>32 = B-region bytes) -> feeds only
  // discarded C rows 33..47 (C[m][n] depends only on A row m). 28.2KB total.
  __shared__ __align__(16) unsigned short lds[4][WROWS * 72];
  int seg_id = blockIdx.x / CHA, c = blockIdx.x % CHA;
  int a = seg_id / SLICES;
  int tid = threadIdx.x, lane = tid & 63, w = tid >> 6;
  unsigned short* SB = &lds[w][0];

  { // zero this wave's region (A stale cols must not be NaN; 441 i32x4)
    i32x4 z = {0, 0, 0, 0};
    i32x4* zp = (i32x4*)SB;
    #pragma unroll
    for (int t = 0; t < 7; ++t) {
      int idx = lane + t * 64;
      if (idx < (WROWS * 72) / 8) zp[idx] = z;
    }
  }

  unsigned thr = thrv[a];                  // precomputed: no per-block scan
  int total = min((int)cnt[seg_id], scap);
  const unsigned* lstb = bitsArr + (size_t)seg_id * scap;
  const uint2*    lstp = pay     + (size_t)seg_id * scap;

  f32x4 acc0 = {0,0,0,0}, acc1 = {0,0,0,0}, acc2 = {0,0,0,0};
  int m = lane & 15, q = lane >> 4;
  const float SQRT2 = 1.41421356237309515f;
  const float PIF   = 3.14159265358979323846f;
  const float S3    = 1.73205080756887729f;

  for (int jb = c * 256 + w * 64; jb < total; jb += CHA * 256) {
    int j = jb + lane;
    bool valid = j < total;
    unsigned bits = valid ? lstb[j] : 0xFFFFFFFFu;
    uint2 pr = make_uint2(0u, 0u);
    if (valid) pr = lstp[j];
    bool live = valid && ((bits >> 9) <= thr);   // stored => d2 < 25 => rn < 1
    if (live) {
      float d2 = __uint_as_float(bits);
      __half2 hxy = *reinterpret_cast<const __half2*>(&pr.x);
      __half2 hzn = *reinterpret_cast<const __half2*>(&pr.y);
      float dx = __low2float(hxy), dy = __high2float(hxy);
      float dz = __low2float(hzn), nw = __high2float(hzn);
#if __has_builtin(__builtin_amdgcn_sqrtf)
      float rn = __builtin_amdgcn_sqrtf(d2) * 0.2f;
#else
      float rn = sqrtf(d2) * 0.2f;
#endif
      float x2 = rn * rn;
      float x6 = x2 * x2 * x2;
      float e  = __fmaf_rn(x6, __fmaf_rn(-21.f, x2, __fmaf_rn(48.f, rn, -28.f)), 1.f);
      float f  = SQRT2 * e;
#if __has_builtin(__builtin_amdgcn_rcpf)
      float inv = 0.2f * __builtin_amdgcn_rcpf(rn + 1e-15f);
#else
      float inv = 0.2f / (rn + 1e-15f);
#endif
      float X = dx * inv, Y = dy * inv, Z = dz * inv;
      float r2 = __fmaf_rn(X, X, __fmaf_rn(Y, Y, Z * Z));
      // B rows: v[h] = nw * sh[h]
      SB[BBASE + 0*72 + lane] = tobf(nw);
      SB[BBASE + 1*72 + lane] = tobf(nw * Y);
      SB[BBASE + 2*72 + lane] = tobf(nw * Z);
      SB[BBASE + 3*72 + lane] = tobf(nw * X);
      SB[BBASE + 4*72 + lane] = tobf(nw * S3 * X * Y);
      SB[BBASE + 5*72 + lane] = tobf(nw * S3 * Y * Z);
      SB[BBASE + 6*72 + lane] = tobf(nw * 0.5f * __fmaf_rn(3.f, Z * Z, -r2));
      SB[BBASE + 7*72 + lane] = tobf(nw * S3 * X * Z);
      SB[BBASE + 8*72 + lane] = tobf(nw * 0.5f * S3 * (X * X - Y * Y));
      // A rows: rbf[r] = sqrt2*e*[0.1, sin(k pi r), cos(k pi r)] (recurrence)
      float s1, c1;
      __sincosf(PIF * rn, &s1, &c1);
      SB[0 * 72 + lane]  = tobf(0.1f * f);
      float sk = s1, ck = c1;
      SB[1 * 72 + lane]  = tobf(f * sk);
      SB[17 * 72 + lane] = tobf(f * ck);
      #pragma unroll
      for (int k = 2; k <= 16; ++k) {
        float sn = __fmaf_rn(sk, c1, ck * s1);
        float cn = __fmaf_rn(ck, c1, -(sk * s1));
        sk = sn; ck = cn;
        SB[k * 72 + lane]        = tobf(f * sk);
        SB[(16 + k) * 72 + lane] = tobf(f * ck);
      }
    } else {
      // zero B column -> this point contributes nothing (A may be stale)
      #pragma unroll
      for (int h = 0; h < 9; ++h) SB[BBASE + h * 72 + lane] = 0;
    }
    // MFMA: A[m=r][k=p], B[k=p][n=h]; lane m=l&15, k=8*(l>>4)+j (+32 per k-group)
    #pragma unroll
    for (int g = 0; g < 2; ++g) {
      int cb = 8 * q + 32 * g;
      i32x4 bf = *(const i32x4*)&SB[BBASE + m * 72 + cb];
      i32x4 a0 = *(const i32x4*)&SB[(0  + m) * 72 + cb];
      mfma_acc(acc0, a0, bf);
      i32x4 a1 = *(const i32x4*)&SB[(16 + m) * 72 + cb];
      mfma_acc(acc1, a1, bf);
      i32x4 a2 = *(const i32x4*)&SB[(32 + m) * 72 + cb];
      mfma_acc(acc2, a2, bf);
    }
  }
  // MFMA -> VALU read hazard guard
  asm volatile("s_nop 7\n\ts_nop 7" : "+v"(acc0), "+v"(acc1), "+v"(acc2));

  // cross-wave reduction in LDS (wave-private regions)
  float* redw = (float*)&lds[w][0];
  if (m < 9) {
    #pragma unroll
    for (int t = 0; t < 4; ++t) {
      int row = 4 * q + t;                 // C/D: col=lane&15, row=(lane>>4)*4+t
      redw[(row +  0) * 9 + m] = acc0[t];
      redw[(row + 16) * 9 + m] = acc1[t];
      if (row + 32 < 33) redw[(row + 32) * 9 + m] = acc2[t];
    }
  }
  __syncthreads();
  float* pbb = pb + (size_t)blockIdx.x * PBSTR;
  for (int v = tid; v < 297; v += 256) {
    float s0 = ((const float*)&lds[0][0])[v] + ((const float*)&lds[1][0])[v];
    float s1 = ((const float*)&lds[2][0])[v] + ((const float*)&lds[3][0])[v];
    pbb[v] = s0 + s1;                      // plain store -- zero atomics
  }
}

// ---------------- K6: sum chunk partials -> out ----------------
__global__ __launch_bounds__(256) void enc_reduce(
    const float* __restrict__ pb, float* __restrict__ out, int nout) {
  int idx = blockIdx.x * 256 + threadIdx.x;
  if (idx >= nout) return;
  int a = idx / 297, v = idx - a * 297;
  const float* p = pb + (size_t)a * NCHUNK * PBSTR + v;
  float s = 0.f;
  #pragma unroll 8
  for (int k = 0; k < NCHUNK; ++k) s += p[(size_t)k * PBSTR];
  out[idx] = s;
}

extern "C" void kernel_launch(void* const* d_in, const int* in_sizes, int n_in,
                              void* d_out, int out_size, void* d_ws, size_t ws_size,
                              hipStream_t stream) {
  const float* nuc  = (const float*)d_in[0];
  // d_in[1] = atom_mask (unused by reference math)
  const float* grid = (const float*)d_in[2];
  const float* wts  = (const float*)d_in[3];
  const float* nn   = (const float*)d_in[4];
  int A = in_sizes[0] / 3;
  int N = in_sizes[2] / 3;
  long long t8 = (8LL * (long long)N) / (long long)A;
  unsigned T = (unsigned)(t8 < (long long)N ? t8 : (long long)N);

  // ws: [cnt A*S][b1 A][r2 A][thr A][hists A*S*NB1][ghist2 A*NB2]
  //     [pb A*S*CHA*PBSTR floats][bits A*S*SCAP u32][pay A*S*SCAP uint2]
  unsigned* ws      = (unsigned*)d_ws;
  unsigned* cnt     = ws;
  unsigned* b1r     = cnt + A * SLICES;
  unsigned* r2r     = b1r + A;
  unsigned* thr     = r2r + A;
  unsigned* hists   = thr + A;
  unsigned* ghist2  = hists + (size_t)A * SLICES * NB1;
  float*    pb      = (float*)(ghist2 + (size_t)A * NB2);
  unsigned* bitsArr = (unsigned*)(pb + (size_t)A * SLICES * CHA * PBSTR);

  // per-slice quad range bounds the stored count -> overflow impossible
  int nq   = N >> 2;
  int qper = (nq + SLICES - 1) / SLICES;
  int SCAP = qper * 4 + 4;
  {
    long long head  = (long long)(bitsArr - ws);               // dwords
    long long avail = (long long)(ws_size / 4) - head;         // dwords
    long long need  = 3LL * SCAP * A * SLICES;                 // 1 + 2 dwords
    if (avail > 0 && need > avail) SCAP = (int)(avail / (3LL * A * SLICES));
    SCAP &= ~1;                                                // keep pay 8B-aligned
  }
  uint2* pay = (uint2*)(bitsArr + (size_t)A * SLICES * SCAP);
  float* out = (float*)d_out;
  int nout = A * 297;

  enc_hist_store<<<A * SLICES,         256, 0, stream>>>(nuc, grid, wts, nn, N, hists,
                                                         cnt, bitsArr, pay, SCAP, ghist2);
  enc_scan1     <<<A,                  256, 0, stream>>>(hists, T, b1r, r2r);
  enc_fine      <<<A * SLICES,         256, 0, stream>>>(b1r, cnt, bitsArr, SCAP, ghist2);
  enc_scan2     <<<A,                  256, 0, stream>>>(ghist2, b1r, r2r, thr);
  enc_accum     <<<A * SLICES * CHA,   256, 0, stream>>>(thr, cnt, bitsArr, pay, SCAP, pb);
  enc_reduce    <<<(nout + 255) / 256, 256, 0, stream>>>(pb, out, nout);
}

// Round 16
// 57.519 us; speedup vs baseline: 1.3696x; 1.1094x over previous
//
#include <hip/hip_runtime.h>
#include <hip/hip_fp16.h>

// Encoder: per-atom top-T nearest grid points -> sum_t rbf[33] (x) (sh[9]*n*w)
// R15 lesson: accum runs ~1.5 main-loop iters/wave -- per-block fixed costs
// and exposed record-load latency dominate. R16: CHA=1 (3 iters/wave) +
// software prefetch of next record across the ~600cy feature computation.
// 6 dispatches:
// K1 hist_store: full scan; 256-bin clamped coarse hist; append bits(4B) +
//                payload(8B: f16 dx,dy,dz,nw); zero ghist2 stripe
// K2 scan1     : per-atom: sum 32x256-bin hists -> b1, residual R2
// K3 fine      : fine hist bits[17:9] of crossing-bin points (bits-only)
// K4 scan2     : per-atom: scan 512-bin fine hist -> thr[a]
// K5 accum     : thr scalar; prefetch records, filter, features, bf16 MFMA,
//                LDS cross-wave reduce, one plain 297-float store per block
// K6 reduce    : sum 32 chunk-partials per atom -> out

typedef float f32x4 __attribute__((ext_vector_type(4)));
typedef int   i32x4 __attribute__((ext_vector_type(4)));

#define SLICES 32
#define NB1    256           // coarse bins (clamped)
#define NB2    512           // fine bins: bits[17:9] within crossing bin
#define CLAMP0 4000u         // bits>>18 below this (d2<~0.25) -> bin 0
#define CHA    1             // accum chunks per segment
#define NCHUNK (SLICES * CHA)
#define PBSTR  304           // partials row stride
#define CUT25  0x41C80000u   // __float_as_uint(25.0f) == CUTOFF^2 bits
#define WROWS  49            // accum: 33 A rows + 16 B rows per wave
#define BBASE  (33 * 72)     // B region offset (shorts)

__device__ __forceinline__ unsigned short tobf(float v) {
  return (unsigned short)((__float_as_uint(v) + 0x8000u) >> 16);
}

__device__ __forceinline__ unsigned pack2h(float a, float b) {
  __half2 h = __floats2half2_rn(a, b);
  return *reinterpret_cast<unsigned*>(&h);
}

__device__ __forceinline__ void mfma_acc(f32x4& d, i32x4 a, i32x4 b) {
  asm("v_mfma_f32_16x16x32_bf16 %0, %1, %2, %0" : "+v"(d) : "v"(a), "v"(b));
}

// ---------------- K1: full scan -> coarse hist + bits/payload append ----------------
__global__ __launch_bounds__(256) void enc_hist_store(
    const float* __restrict__ nuc, const float* __restrict__ grid,
    const float* __restrict__ wv, const float* __restrict__ nv, int N,
    unsigned* __restrict__ hists, unsigned* __restrict__ cnt,
    unsigned* __restrict__ bitsArr, uint2* __restrict__ pay, int scap,
    unsigned* __restrict__ ghist2) {
  __shared__ unsigned lh[NB1];
  __shared__ unsigned s_cnt;
  int a = blockIdx.x / SLICES, s = blockIdx.x % SLICES;
  int tid = threadIdx.x, lane = tid & 63;
  if (tid < NB1) lh[tid] = 0;
  if (tid == 0) s_cnt = 0;
  { // zero this block's stripe of atom a's fine hist (written by K3 later)
    const int stripe = NB2 / SLICES;       // 16
    if (tid < stripe) ghist2[(size_t)a * NB2 + s * stripe + tid] = 0;
  }
  __syncthreads();

  float px = nuc[3*a+0], py = nuc[3*a+1], pz = nuc[3*a+2];
  unsigned* segb = bitsArr + (size_t)blockIdx.x * scap;
  uint2*    segp = pay     + (size_t)blockIdx.x * scap;
  const float4* G4 = (const float4*)grid;
  const float4* W4 = (const float4*)wv;
  const float4* V4 = (const float4*)nv;
  int nq = N >> 2;
  int qper = (nq + SLICES - 1) / SLICES;
  int qlo = s * qper, qhi = min(nq, qlo + qper);

  for (int qi = qlo + tid; qi < qhi; qi += 256) {
    float4 A4 = G4[3*qi], B4 = G4[3*qi+1], C4 = G4[3*qi+2];
    float4 w4 = W4[qi], v4 = V4[qi];
    float xs[4] = {A4.x, A4.w, B4.z, C4.y};
    float ys[4] = {A4.y, B4.x, B4.w, C4.z};
    float zs[4] = {A4.z, B4.y, C4.x, C4.w};
    float nws[4] = {v4.x * w4.x, v4.y * w4.y, v4.z * w4.z, v4.w * w4.w};
    float dxs[4], dys[4], dzs[4];
    unsigned bt[4];
    #pragma unroll
    for (int k = 0; k < 4; ++k) {
      float dx = px - xs[k], dy = py - ys[k], dz = pz - zs[k];
      dxs[k] = dx; dys[k] = dy; dzs[k] = dz;
      float d2 = __fmaf_rn(dx, dx, __fmaf_rn(dy, dy, __fmul_rn(dz, dz)));
      bt[k] = __float_as_uint(d2);
      if (bt[k] < CUT25) {
        int cb = (int)(bt[k] >> 18) - (int)CLAMP0;
        atomicAdd(&lh[cb > 0 ? cb : 0], 1u);
      }
    }
    #pragma unroll
    for (int k = 0; k < 4; ++k) {
      bool sel = bt[k] < CUT25;                    // envelope != 0 only here
      unsigned long long mm = __ballot(sel);
      if (mm) {
        int leader = __ffsll(mm) - 1;
        unsigned base = 0;
        if (lane == leader) base = atomicAdd(&s_cnt, (unsigned)__popcll(mm));
        base = __shfl(base, leader);
        if (sel) {
          unsigned pos = base + (unsigned)__popcll(mm & ((1ull << lane) - 1ull));
          if (pos < (unsigned)scap) {
            segb[pos] = bt[k];
            segp[pos] = make_uint2(pack2h(dxs[k], dys[k]), pack2h(dzs[k], nws[k]));
          }
        }
      }
    }
  }
  if (s == SLICES - 1) {                   // scalar tail (N % 4 points)
    for (int i = 4*nq + tid; i < N; i += 256) {
      float dx = px - grid[3*i+0], dy = py - grid[3*i+1], dz = pz - grid[3*i+2];
      float d2 = __fmaf_rn(dx, dx, __fmaf_rn(dy, dy, __fmul_rn(dz, dz)));
      unsigned bits = __float_as_uint(d2);
      bool sel = bits < CUT25;
      if (sel) {
        int cb = (int)(bits >> 18) - (int)CLAMP0;
        atomicAdd(&lh[cb > 0 ? cb : 0], 1u);
      }
      unsigned long long mm = __ballot(sel);
      if (mm) {
        int leader = __ffsll(mm) - 1;
        unsigned base = 0;
        if (lane == leader) base = atomicAdd(&s_cnt, (unsigned)__popcll(mm));
        base = __shfl(base, leader);
        if (sel) {
          unsigned pos = base + (unsigned)__popcll(mm & ((1ull << lane) - 1ull));
          if (pos < (unsigned)scap) {
            segb[pos] = bits;
            segp[pos] = make_uint2(pack2h(dx, dy), pack2h(dz, nv[i] * wv[i]));
          }
        }
      }
    }
  }
  __syncthreads();
  if (tid < NB1) hists[(size_t)blockIdx.x * NB1 + tid] = lh[tid];  // plain store
  if (tid == 0) cnt[blockIdx.x] = s_cnt;
}

// ---------------- K2: per-atom coarse scan -> b1, R2 ----------------
__global__ __launch_bounds__(256) void enc_scan1(
    const unsigned* __restrict__ hists, unsigned T,
    unsigned* __restrict__ b1r, unsigned* __restrict__ r2r) {
  __shared__ unsigned lh[NB1];
  __shared__ unsigned s_bin, s_pre;
  int a = blockIdx.x, tid = threadIdx.x;
  if (tid < NB1) {
    unsigned acc = 0;
    const unsigned* base = hists + (size_t)a * SLICES * NB1 + tid;
    #pragma unroll 8
    for (int t = 0; t < SLICES; ++t) acc += base[(size_t)t * NB1];
    lh[tid] = acc;
  }
  if (tid == 0) { s_bin = NB1 - 1; s_pre = 0; }
  __syncthreads();
  if (tid < 64) {
    int lane = tid, base = 4 * lane;
    unsigned h0 = lh[base], h1 = lh[base+1], h2 = lh[base+2], h3 = lh[base+3];
    unsigned ssum = h0 + h1 + h2 + h3;
    unsigned p = ssum;
    #pragma unroll
    for (int d = 1; d < 64; d <<= 1) {
      unsigned t = __shfl_up(p, d);
      if (lane >= d) p += t;
    }
    unsigned excl = p - ssum;
    if (excl < T && T <= p) {              // unique crossing lane
      unsigned cum = excl;
      unsigned hh[4] = {h0, h1, h2, h3};
      #pragma unroll
      for (int k = 0; k < 4; ++k) {
        if (cum + hh[k] >= T) { s_bin = (unsigned)(base + k); s_pre = cum; break; }
        cum += hh[k];
      }
    }
  }
  __syncthreads();
  if (tid == 0) { b1r[a] = s_bin; r2r[a] = T - s_pre; }
}

// ---------------- K3: fine hist of crossing-bin points (bits-only) ----------------
__global__ __launch_bounds__(256) void enc_fine(
    const unsigned* __restrict__ b1r, const unsigned* __restrict__ cnt,
    const unsigned* __restrict__ bitsArr, int scap,
    unsigned* __restrict__ ghist2) {
  int seg_id = blockIdx.x;
  int a = seg_id / SLICES;
  unsigned b1c = b1r[a];
  unsigned tb1 = b1c + CLAMP0;
  int total = min((int)cnt[seg_id], scap);
  const unsigned* segb = bitsArr + (size_t)seg_id * scap;
  unsigned* gh2 = ghist2 + (size_t)a * NB2;
  for (int i = threadIdx.x; i < total; i += 256) {
    unsigned bits = segb[i];
    unsigned cb = bits >> 18;
    bool match = b1c ? (cb == tb1) : (cb <= CLAMP0);  // bin0 = clamped region
    if (match) atomicAdd(&gh2[(bits >> 9) & (NB2 - 1)], 1u);
  }
}

// ---------------- K4: per-atom fine scan -> thr ----------------
__global__ __launch_bounds__(256) void enc_scan2(
    const unsigned* __restrict__ ghist2, const unsigned* __restrict__ b1r,
    const unsigned* __restrict__ r2r, unsigned* __restrict__ thr) {
  __shared__ unsigned lh2[NB2];
  __shared__ unsigned s_bin2;
  int a = blockIdx.x, tid = threadIdx.x;
  const unsigned* gh2 = ghist2 + (size_t)a * NB2;
  lh2[tid] = gh2[tid];
  lh2[tid + 256] = gh2[tid + 256];
  if (tid == 0) s_bin2 = NB2 - 1;
  __syncthreads();
  unsigned R = r2r[a];
  if (tid < 64) {                          // two-level scan over 512 bins
    int lane = tid, base = 8 * lane;
    unsigned hh[8], ssum = 0;
    #pragma unroll
    for (int k = 0; k < 8; ++k) { hh[k] = lh2[base + k]; ssum += hh[k]; }
    unsigned p = ssum;
    #pragma unroll
    for (int d = 1; d < 64; d <<= 1) {
      unsigned t = __shfl_up(p, d);
      if (lane >= d) p += t;
    }
    unsigned excl = p - ssum;
    if (excl < R && R <= p) {
      unsigned cum = excl;
      #pragma unroll
      for (int k = 0; k < 8; ++k) {
        if (cum + hh[k] >= R) { s_bin2 = (unsigned)(base + k); break; }
        cum += hh[k];
      }
    }
  }
  __syncthreads();
  if (tid == 0) thr[a] = ((b1r[a] + CLAMP0) << 9) | s_bin2;  // (bits>>9) <= thr
}

// ---------------- K5: MFMA accumulation -> per-block partials ----------------
__global__ __launch_bounds__(256, 5) void enc_accum(
    const unsigned* __restrict__ thrv, const unsigned* __restrict__ cnt,
    const unsigned* __restrict__ bitsArr, const uint2* __restrict__ pay,
    int scap, float* __restrict__ pb) {
  // per-wave 49-row x 72-short region: A rows 0..32, B rows 33..48.
  // MFMA a2 reads rows 32..47 (rows>32 = B-region bytes) -> feeds only
  // discarded C rows 33..47 (C[m][n] depends only on A row m). 28.2KB total.
  __shared__ __align__(16) unsigned short lds[4][WROWS * 72];
  int seg_id = blockIdx.x;                 // CHA == 1
  int a = seg_id / SLICES;
  int tid = threadIdx.x, lane = tid & 63, w = tid >> 6;
  unsigned short* SB = &lds[w][0];

  { // zero this wave's region (A stale cols must not be NaN; 441 i32x4)
    i32x4 z = {0, 0, 0, 0};
    i32x4* zp = (i32x4*)SB;
    #pragma unroll
    for (int t = 0; t < 7; ++t) {
      int idx = lane + t * 64;
      if (idx < (WROWS * 72) / 8) zp[idx] = z;
    }
  }

  unsigned thr = thrv[a];                  // precomputed: no per-block scan
  int total = min((int)cnt[seg_id], scap);
  const unsigned* lstb = bitsArr + (size_t)seg_id * scap;
  const uint2*    lstp = pay     + (size_t)seg_id * scap;

  f32x4 acc0 = {0,0,0,0}, acc1 = {0,0,0,0}, acc2 = {0,0,0,0};
  int m = lane & 15, q = lane >> 4;
  const float SQRT2 = 1.41421356237309515f;
  const float PIF   = 3.14159265358979323846f;
  const float S3    = 1.73205080756887729f;

  // software prefetch: issue next record's loads before the ~600cy body
  int j0 = w * 64 + lane;
  unsigned bitsN = (j0 < total) ? lstb[j0] : 0xFFFFFFFFu;
  uint2 prN = make_uint2(0u, 0u);
  if (j0 < total) prN = lstp[j0];

  for (int jb = w * 64; jb < total; jb += 256) {
    unsigned bits = bitsN;
    uint2 pr = prN;
    int jn = jb + 256 + lane;
    if (jn < total) { bitsN = lstb[jn]; prN = lstp[jn]; }
    bool live = (jb + lane < total) && ((bits >> 9) <= thr);
    if (live) {
      float d2 = __uint_as_float(bits);
      __half2 hxy = *reinterpret_cast<const __half2*>(&pr.x);
      __half2 hzn = *reinterpret_cast<const __half2*>(&pr.y);
      float dx = __low2float(hxy), dy = __high2float(hxy);
      float dz = __low2float(hzn), nw = __high2float(hzn);
#if __has_builtin(__builtin_amdgcn_sqrtf)
      float rn = __builtin_amdgcn_sqrtf(d2) * 0.2f;
#else
      float rn = sqrtf(d2) * 0.2f;
#endif
      float x2 = rn * rn;
      float x6 = x2 * x2 * x2;
      float e  = __fmaf_rn(x6, __fmaf_rn(-21.f, x2, __fmaf_rn(48.f, rn, -28.f)), 1.f);
      float f  = SQRT2 * e;
#if __has_builtin(__builtin_amdgcn_rcpf)
      float inv = 0.2f * __builtin_amdgcn_rcpf(rn + 1e-15f);
#else
      float inv = 0.2f / (rn + 1e-15f);
#endif
      float X = dx * inv, Y = dy * inv, Z = dz * inv;
      float r2 = __fmaf_rn(X, X, __fmaf_rn(Y, Y, Z * Z));
      // B rows: v[h] = nw * sh[h]
      SB[BBASE + 0*72 + lane] = tobf(nw);
      SB[BBASE + 1*72 + lane] = tobf(nw * Y);
      SB[BBASE + 2*72 + lane] = tobf(nw * Z);
      SB[BBASE + 3*72 + lane] = tobf(nw * X);
      SB[BBASE + 4*72 + lane] = tobf(nw * S3 * X * Y);
      SB[BBASE + 5*72 + lane] = tobf(nw * S3 * Y * Z);
      SB[BBASE + 6*72 + lane] = tobf(nw * 0.5f * __fmaf_rn(3.f, Z * Z, -r2));
      SB[BBASE + 7*72 + lane] = tobf(nw * S3 * X * Z);
      SB[BBASE + 8*72 + lane] = tobf(nw * 0.5f * S3 * (X * X - Y * Y));
      // A rows: rbf[r] = sqrt2*e*[0.1, sin(k pi r), cos(k pi r)] (recurrence)
      float s1, c1;
      __sincosf(PIF * rn, &s1, &c1);
      SB[0 * 72 + lane]  = tobf(0.1f * f);
      float sk = s1, ck = c1;
      SB[1 * 72 + lane]  = tobf(f * sk);
      SB[17 * 72 + lane] = tobf(f * ck);
      #pragma unroll
      for (int k = 2; k <= 16; ++k) {
        float sn = __fmaf_rn(sk, c1, ck * s1);
        float cn = __fmaf_rn(ck, c1, -(sk * s1));
        sk = sn; ck = cn;
        SB[k * 72 + lane]        = tobf(f * sk);
        SB[(16 + k) * 72 + lane] = tobf(f * ck);
      }
    } else {
      // zero B column -> this point contributes nothing (A may be stale)
      #pragma unroll
      for (int h = 0; h < 9; ++h) SB[BBASE + h * 72 + lane] = 0;
    }
    // MFMA: A[m=r][k=p], B[k=p][n=h]; lane m=l&15, k=8*(l>>4)+j (+32 per k-group)
    #pragma unroll
    for (int g = 0; g < 2; ++g) {
      int cb = 8 * q + 32 * g;
      i32x4 bf = *(const i32x4*)&SB[BBASE + m * 72 + cb];
      i32x4 a0 = *(const i32x4*)&SB[(0  + m) * 72 + cb];
      mfma_acc(acc0, a0, bf);
      i32x4 a1 = *(const i32x4*)&SB[(16 + m) * 72 + cb];
      mfma_acc(acc1, a1, bf);
      i32x4 a2 = *(const i32x4*)&SB[(32 + m) * 72 + cb];
      mfma_acc(acc2, a2, bf);
    }
  }
  // MFMA -> VALU read hazard guard
  asm volatile("s_nop 7\n\ts_nop 7" : "+v"(acc0), "+v"(acc1), "+v"(acc2));

  // cross-wave reduction in LDS (wave-private regions)
  float* redw = (float*)&lds[w][0];
  if (m < 9) {
    #pragma unroll
    for (int t = 0; t < 4; ++t) {
      int row = 4 * q + t;                 // C/D: col=lane&15, row=(lane>>4)*4+t
      redw[(row +  0) * 9 + m] = acc0[t];
      redw[(row + 16) * 9 + m] = acc1[t];
      if (row + 32 < 33) redw[(row + 32) * 9 + m] = acc2[t];
    }
  }
  __syncthreads();
  float* pbb = pb + (size_t)blockIdx.x * PBSTR;
  for (int v = tid; v < 297; v += 256) {
    float s0 = ((const float*)&lds[0][0])[v] + ((const float*)&lds[1][0])[v];
    float s1 = ((const float*)&lds[2][0])[v] + ((const float*)&lds[3][0])[v];
    pbb[v] = s0 + s1;                      // plain store -- zero atomics
  }
}

// ---------------- K6: sum chunk partials -> out ----------------
__global__ __launch_bounds__(256) void enc_reduce(
    const float* __restrict__ pb, float* __restrict__ out, int nout) {
  int idx = blockIdx.x * 256 + threadIdx.x;
  if (idx >= nout) return;
  int a = idx / 297, v = idx - a * 297;
  const float* p = pb + (size_t)a * NCHUNK * PBSTR + v;
  float s = 0.f;
  #pragma unroll 8
  for (int k = 0; k < NCHUNK; ++k) s += p[(size_t)k * PBSTR];
  out[idx] = s;
}

extern "C" void kernel_launch(void* const* d_in, const int* in_sizes, int n_in,
                              void* d_out, int out_size, void* d_ws, size_t ws_size,
                              hipStream_t stream) {
  const float* nuc  = (const float*)d_in[0];
  // d_in[1] = atom_mask (unused by reference math)
  const float* grid = (const float*)d_in[2];
  const float* wts  = (const float*)d_in[3];
  const float* nn   = (const float*)d_in[4];
  int A = in_sizes[0] / 3;
  int N = in_sizes[2] / 3;
  long long t8 = (8LL * (long long)N) / (long long)A;
  unsigned T = (unsigned)(t8 < (long long)N ? t8 : (long long)N);

  // ws: [cnt A*S][b1 A][r2 A][thr A][hists A*S*NB1][ghist2 A*NB2]
  //     [pb A*S*CHA*PBSTR floats][bits A*S*SCAP u32][pay A*S*SCAP uint2]
  unsigned* ws      = (unsigned*)d_ws;
  unsigned* cnt     = ws;
  unsigned* b1r     = cnt + A * SLICES;
  unsigned* r2r     = b1r + A;
  unsigned* thr     = r2r + A;
  unsigned* hists   = thr + A;
  unsigned* ghist2  = hists + (size_t)A * SLICES * NB1;
  float*    pb      = (float*)(ghist2 + (size_t)A * NB2);
  unsigned* bitsArr = (unsigned*)(pb + (size_t)A * SLICES * CHA * PBSTR);

  // per-slice quad range bounds the stored count -> overflow impossible
  int nq   = N >> 2;
  int qper = (nq + SLICES - 1) / SLICES;
  int SCAP = qper * 4 + 4;
  {
    long long head  = (long long)(bitsArr - ws);               // dwords
    long long avail = (long long)(ws_size / 4) - head;         // dwords
    long long need  = 3LL * SCAP * A * SLICES;                 // 1 + 2 dwords
    if (avail > 0 && need > avail) SCAP = (int)(avail / (3LL * A * SLICES));
    SCAP &= ~1;                                                // keep pay 8B-aligned
  }
  uint2* pay = (uint2*)(bitsArr + (size_t)A * SLICES * SCAP);
  float* out = (float*)d_out;
  int nout = A * 297;

  enc_hist_store<<<A * SLICES,         256, 0, stream>>>(nuc, grid, wts, nn, N, hists,
                                                         cnt, bitsArr, pay, SCAP, ghist2);
  enc_scan1     <<<A,                  256, 0, stream>>>(hists, T, b1r, r2r);
  enc_fine      <<<A * SLICES,         256, 0, stream>>>(b1r, cnt, bitsArr, SCAP, ghist2);
  enc_scan2     <<<A,                  256, 0, stream>>>(ghist2, b1r, r2r, thr);
  enc_accum     <<<A * SLICES * CHA,   256, 0, stream>>>(thr, cnt, bitsArr, pay, SCAP, pb);
  enc_reduce    <<<(nout + 255) / 256, 256, 0, stream>>>(pb, out, nout);
}